// Round 1
// baseline (793.456 us; speedup 1.0000x reference)
//
#include <hip/hip_runtime.h>
#include <math.h>

#define EDIM 128
#define NHEAD 16
#define HDIM 8
#define SEQ 2048
#define BATCH 4
#define NROW (BATCH*SEQ)            // 8192
#define ATTN_SCALE 0.35355339059327373f   // 8^-0.5

// ---------------------------------------------------------------------------
// Transpose the 4 weight matrices W[j][i] -> WT[i][j] so the GEMM contraction
// can read W coalesced along lanes. grid=(8,4), block=256.
// ---------------------------------------------------------------------------
__global__ __launch_bounds__(256)
void transpose4_kernel(const float* __restrict__ W0, const float* __restrict__ W1,
                       const float* __restrict__ W2, const float* __restrict__ W3,
                       float* __restrict__ WT)
{
  const float* W = (blockIdx.y == 0) ? W0 : (blockIdx.y == 1) ? W1
                 : (blockIdx.y == 2) ? W2 : W3;
  float* out = WT + blockIdx.y * EDIM * EDIM;
  const int i0 = blockIdx.x * 16;                 // 16 WT-rows per block
  #pragma unroll
  for (int it = 0; it < 8; ++it) {
    int f = threadIdx.x + it * 256;               // 0..2047 over 16 i x 128 j
    int i = i0 + (f >> 7);
    int j = f & 127;
    out[i * EDIM + j] = W[j * EDIM + i];          // write coalesced, read L1-cached
  }
}

// ---------------------------------------------------------------------------
// out = X @ W^T + b, using pre-transposed WT[i][j].
// Block: 256 threads, 64 rows x 128 cols tile. Thread: 8 rows x 4 cols.
// MODE 0: scatter to q/k/v layout [B,H,S,D]; MODE 1: row-major [rows, E].
// Per i-step: 1 coalesced float4 (WT) + 8 broadcast LDS b32 (x) + 32 FMA.
// ---------------------------------------------------------------------------
template<int MODE>
__device__ __forceinline__
void proj_body(const float* __restrict__ X, const float* __restrict__ WT,
               const float* __restrict__ bias, float* __restrict__ out)
{
  __shared__ float xs[64][EDIM];                  // 32 KB
  const int tid = threadIdx.x;
  const int row0 = blockIdx.x * 64;

  const float4* src = (const float4*)(X + row0 * EDIM);
  float4* dst = (float4*)(&xs[0][0]);
  #pragma unroll
  for (int t = 0; t < 8; ++t) dst[tid + t * 256] = src[tid + t * 256];
  __syncthreads();

  const int tc = tid & 31;
  const int tr = tid >> 5;                        // 0..7
  const int col0 = tc * 4;

  float acc[8][4];
  #pragma unroll
  for (int r = 0; r < 8; ++r)
    #pragma unroll
    for (int c = 0; c < 4; ++c) acc[r][c] = 0.f;

  #pragma unroll 4
  for (int i = 0; i < EDIM; ++i) {
    const float4 w4 = *(const float4*)(WT + i * EDIM + col0);
    #pragma unroll
    for (int r = 0; r < 8; ++r) {
      const float xr = xs[tr * 8 + r][i];         // half-wave-uniform -> broadcast
      acc[r][0] += xr * w4.x;
      acc[r][1] += xr * w4.y;
      acc[r][2] += xr * w4.z;
      acc[r][3] += xr * w4.w;
    }
  }

  const float4 b4 = *(const float4*)(bias + col0);
  #pragma unroll
  for (int r = 0; r < 8; ++r) {
    const int grow = row0 + tr * 8 + r;
    const float4 o = make_float4(acc[r][0] + b4.x, acc[r][1] + b4.y,
                                 acc[r][2] + b4.z, acc[r][3] + b4.w);
    if (MODE == 0) {
      const int b = grow >> 11, s = grow & (SEQ - 1);
      const int h = col0 >> 3, d0 = col0 & 7;     // cols col0..col0+3 share h; d0 in {0,4}
      *(float4*)(out + (((b * NHEAD + h) * SEQ + s) * HDIM + d0)) = o;
    } else {
      *(float4*)(out + grow * EDIM + col0) = o;
    }
  }
}

__global__ __launch_bounds__(256)
void qkv_kernel(const float* __restrict__ X, const float* __restrict__ WT,
                const float* __restrict__ bq, const float* __restrict__ bk,
                const float* __restrict__ bv,
                float* __restrict__ q, float* __restrict__ k, float* __restrict__ v)
{
  const int m = blockIdx.y;
  const float* wt  = WT + m * EDIM * EDIM;
  const float* bias = (m == 0) ? bq : (m == 1) ? bk : bv;
  float* out        = (m == 0) ? q  : (m == 1) ? k  : v;
  proj_body<0>(X, wt, bias, out);
}

__global__ __launch_bounds__(256)
void oproj_kernel(const float* __restrict__ A, const float* __restrict__ WTo,
                  const float* __restrict__ bo, float* __restrict__ out)
{
  proj_body<1>(A, WTo, bo, out);
}

// ---------------------------------------------------------------------------
// Causal sigmoid-attention. One wave per 64 consecutive query rows of one
// (b,h). Lane = query row; K/V rows are wave-uniform -> scalar broadcast
// loads; no cross-lane reductions. Masked keys (k>q) contribute exactly 0
// to numerator and denominator (sigmoid(-1e9)==0), so exec-masking is exact.
// grid = B*H*S/64 = 2048 blocks of 64 threads.
// ---------------------------------------------------------------------------
__global__ __launch_bounds__(64)
void attn_kernel(const float* __restrict__ Q, const float* __restrict__ K,
                 const float* __restrict__ V, float* __restrict__ out)
{
  const int wid  = blockIdx.x;
  const int tile = wid & 31;                      // S/64 tiles per (b,h)
  const int bh   = wid >> 5;                      // 0..63
  const int lane = threadIdx.x;
  const int qrow = tile * 64 + lane;

  const float* qp = Q + (size_t)(bh * SEQ + qrow) * HDIM;
  const float4 qa = *(const float4*)qp;
  const float4 qb = *(const float4*)(qp + 4);
  const float* Kb = K + (size_t)bh * SEQ * HDIM;
  const float* Vb = V + (size_t)bh * SEQ * HDIM;

  float den = 0.f;
  float a0 = 0.f, a1 = 0.f, a2 = 0.f, a3 = 0.f;
  float a4 = 0.f, a5 = 0.f, a6 = 0.f, a7 = 0.f;

  const int nk = tile * 64 + 64;                  // keys 0..nk-1 cover all lanes
  #pragma unroll 4
  for (int kk = 0; kk < nk; ++kk) {
    // wave-uniform addresses -> scalar loads (s_load_dwordx4)
    const float4 ka = *(const float4*)(Kb + kk * HDIM);
    const float4 kb = *(const float4*)(Kb + kk * HDIM + 4);
    const float4 va = *(const float4*)(Vb + kk * HDIM);
    const float4 vb = *(const float4*)(Vb + kk * HDIM + 4);
    if (kk <= qrow) {                             // causal mask via exec
      const float dot = qa.x * ka.x + qa.y * ka.y + qa.z * ka.z + qa.w * ka.w
                      + qb.x * kb.x + qb.y * kb.y + qb.z * kb.z + qb.w * kb.w;
      // sigmoid: v_exp + v_rcp (raw rcp ~1ulp; avoids the non-fastmath div seq)
      const float sg = __builtin_amdgcn_rcpf(1.f + __expf(-dot * ATTN_SCALE));
      den += sg;
      a0 += sg * va.x;  a1 += sg * va.y;  a2 += sg * va.z;  a3 += sg * va.w;
      a4 += sg * vb.x;  a5 += sg * vb.y;  a6 += sg * vb.z;  a7 += sg * vb.w;
    }
  }

  const float inv = __builtin_amdgcn_rcpf(den);   // den >= sigmoid(s_qq) > 0
  const int b = bh >> 4, h = bh & 15;
  float* op = out + ((size_t)(b * SEQ + qrow)) * EDIM + h * HDIM;
  *(float4*)op       = make_float4(a0 * inv, a1 * inv, a2 * inv, a3 * inv);
  *(float4*)(op + 4) = make_float4(a4 * inv, a5 * inv, a6 * inv, a7 * inv);
}

// ---------------------------------------------------------------------------
extern "C" void kernel_launch(void* const* d_in, const int* in_sizes, int n_in,
                              void* d_out, int out_size, void* d_ws, size_t ws_size,
                              hipStream_t stream)
{
  const float* x  = (const float*)d_in[0];
  const float* Wq = (const float*)d_in[1];
  const float* bq = (const float*)d_in[2];
  const float* Wk = (const float*)d_in[3];
  const float* bk = (const float*)d_in[4];
  const float* Wv = (const float*)d_in[5];
  const float* bv = (const float*)d_in[6];
  const float* Wo = (const float*)d_in[7];
  const float* bo = (const float*)d_in[8];

  float* ws = (float*)d_ws;
  const size_t QN = (size_t)BATCH * NHEAD * SEQ * HDIM;   // 1,048,576 floats
  float* q    = ws;
  float* k    = ws + QN;
  float* v    = ws + 2 * QN;
  float* attn = ws + 3 * QN;
  float* WT   = ws + 4 * QN;                               // 4 x 128 x 128 floats

  transpose4_kernel<<<dim3(8, 4), 256, 0, stream>>>(Wq, Wk, Wv, Wo, WT);
  qkv_kernel<<<dim3(NROW / 64, 3), 256, 0, stream>>>(x, WT, bq, bk, bv, q, k, v);
  attn_kernel<<<dim3(BATCH * NHEAD * SEQ / 64), 64, 0, stream>>>(q, k, v, attn);
  oproj_kernel<<<dim3(NROW / 64), 256, 0, stream>>>(attn, WT + 3 * EDIM * EDIM, bo,
                                                    (float*)d_out);
}

// Round 2
// 323.604 us; speedup vs baseline: 2.4519x; 2.4519x over previous
//
#include <hip/hip_runtime.h>
#include <math.h>

#define EDIM 128
#define NHEAD 16
#define HDIM 8
#define SEQ 2048
#define BATCH 4
#define NROW (BATCH*SEQ)            // 8192
// fold softmax scale AND log2(e) into q so sigmoid = rcp(1 + exp2(-dot))
#define QSCALE (0.35355339059327373f * 1.4426950408889634f)

#if __has_builtin(__builtin_amdgcn_exp2f)
#define EXP2F(x) __builtin_amdgcn_exp2f(x)
#else
#define EXP2F(x) exp2f(x)
#endif
#define RCPF(x) __builtin_amdgcn_rcpf(x)

// ---------------------------------------------------------------------------
// Transpose the 4 weight matrices W[j][i] -> WT[i][j].
// ---------------------------------------------------------------------------
__global__ __launch_bounds__(256)
void transpose4_kernel(const float* __restrict__ W0, const float* __restrict__ W1,
                       const float* __restrict__ W2, const float* __restrict__ W3,
                       float* __restrict__ WT)
{
  const float* W = (blockIdx.y == 0) ? W0 : (blockIdx.y == 1) ? W1
                 : (blockIdx.y == 2) ? W2 : W3;
  float* out = WT + blockIdx.y * EDIM * EDIM;
  const int i0 = blockIdx.x * 16;
  #pragma unroll
  for (int it = 0; it < 8; ++it) {
    int f = threadIdx.x + it * 256;
    int i = i0 + (f >> 7);
    int j = f & 127;
    out[i * EDIM + j] = W[j * EDIM + i];
  }
}

// ---------------------------------------------------------------------------
// out = X @ W^T + b with pre-transposed WT. 64 rows x 128 cols per block.
// mode 0: Q -> [bh][s][8]; mode 1: K -> KV[bh][s][0..7];
// mode 2: V -> KV[bh][s][8..15]; mode 3: row-major [rows][128].
// ---------------------------------------------------------------------------
__device__ __forceinline__
void proj_body(const float* __restrict__ X, const float* __restrict__ WT,
               const float* __restrict__ bias, float* __restrict__ out, int mode)
{
  __shared__ float xs[64][EDIM];                  // 32 KB
  const int tid = threadIdx.x;
  const int row0 = blockIdx.x * 64;

  const float4* src = (const float4*)(X + row0 * EDIM);
  float4* dst = (float4*)(&xs[0][0]);
  #pragma unroll
  for (int t = 0; t < 8; ++t) dst[tid + t * 256] = src[tid + t * 256];
  __syncthreads();

  const int tc = tid & 31;
  const int tr = tid >> 5;
  const int col0 = tc * 4;

  float acc[8][4];
  #pragma unroll
  for (int r = 0; r < 8; ++r)
    #pragma unroll
    for (int c = 0; c < 4; ++c) acc[r][c] = 0.f;

  #pragma unroll 4
  for (int i = 0; i < EDIM; ++i) {
    const float4 w4 = *(const float4*)(WT + i * EDIM + col0);
    #pragma unroll
    for (int r = 0; r < 8; ++r) {
      const float xr = xs[tr * 8 + r][i];
      acc[r][0] += xr * w4.x;
      acc[r][1] += xr * w4.y;
      acc[r][2] += xr * w4.z;
      acc[r][3] += xr * w4.w;
    }
  }

  const float4 b4 = *(const float4*)(bias + col0);
  #pragma unroll
  for (int r = 0; r < 8; ++r) {
    const int grow = row0 + tr * 8 + r;
    const float4 o = make_float4(acc[r][0] + b4.x, acc[r][1] + b4.y,
                                 acc[r][2] + b4.z, acc[r][3] + b4.w);
    if (mode == 3) {
      *(float4*)(out + (size_t)grow * EDIM + col0) = o;
    } else {
      const int b = grow >> 11, s = grow & (SEQ - 1);
      const int h = col0 >> 3, d0 = col0 & 7;
      const size_t bhs = (size_t)(b * NHEAD + h) * SEQ + s;
      if (mode == 0)      *(float4*)(out + bhs * 8  + d0) = o;
      else if (mode == 1) *(float4*)(out + bhs * 16 + d0) = o;
      else                *(float4*)(out + bhs * 16 + 8 + d0) = o;
    }
  }
}

__global__ __launch_bounds__(256)
void qkv_kernel(const float* __restrict__ X, const float* __restrict__ WT,
                const float* __restrict__ bq, const float* __restrict__ bk,
                const float* __restrict__ bv,
                float* __restrict__ q, float* __restrict__ kv)
{
  const int m = blockIdx.y;
  const float* wt   = WT + m * EDIM * EDIM;
  const float* bias = (m == 0) ? bq : (m == 1) ? bk : bv;
  float* out        = (m == 0) ? q  : kv;
  proj_body(X, wt, bias, out, m);
}

__global__ __launch_bounds__(256)
void oproj_kernel(const float* __restrict__ A, const float* __restrict__ WTo,
                  const float* __restrict__ bo, float* __restrict__ out)
{
  proj_body(A, WTo, bo, out, 3);
}

// ---------------------------------------------------------------------------
// Causal sigmoid-attention v2.
// Block = 128 threads (2 waves) covering 128 query rows of one (b,h); each
// lane owns 2 rows (lane, lane+64). The 2 waves split key tiles (even/odd)
// and combine partial (den, acc) through LDS at the end.
// K/V staged per-wave into private LDS double buffers with coalesced
// global_load_dwordx4 (in-order vmcnt, software-pipelined); hot-loop reads
// are broadcast ds_read_b128 (conflict-free). Masked keys contribute exactly
// 0 (sigmoid(-1e9)==0 in the reference), so cndmask-zeroing sg is exact.
// blockIdx = rg*64 + bh -> all 16 blocks of one bh share blockIdx%8 (XCD).
// ---------------------------------------------------------------------------
__global__ __launch_bounds__(128)
void attn_kernel(const float* __restrict__ Q, const float* __restrict__ KV,
                 float* __restrict__ out)
{
  __shared__ float stage[2][2][64 * 16];          // [wave][buf] 16 KB
  __shared__ float red[128][9];                   // 4.5 KB partials

  const int bh   = blockIdx.x & 63;
  const int rg   = blockIdx.x >> 6;               // 0..15, 128 rows each
  const int w    = threadIdx.x >> 6;              // wave 0/1
  const int lane = threadIdx.x & 63;
  const int base = rg * 128;
  const int rowA = base + lane;
  const int rowB = base + 64 + lane;

  const float4* gsrc = (const float4*)(KV + (size_t)bh * SEQ * 16);

  float qA[8], qB[8];
  {
    const float* qpA = Q + ((size_t)bh * SEQ + rowA) * 8;
    const float* qpB = Q + ((size_t)bh * SEQ + rowB) * 8;
    const float4 a0 = *(const float4*)qpA, a1 = *(const float4*)(qpA + 4);
    const float4 b0 = *(const float4*)qpB, b1 = *(const float4*)(qpB + 4);
    qA[0] = a0.x * QSCALE; qA[1] = a0.y * QSCALE; qA[2] = a0.z * QSCALE; qA[3] = a0.w * QSCALE;
    qA[4] = a1.x * QSCALE; qA[5] = a1.y * QSCALE; qA[6] = a1.z * QSCALE; qA[7] = a1.w * QSCALE;
    qB[0] = b0.x * QSCALE; qB[1] = b0.y * QSCALE; qB[2] = b0.z * QSCALE; qB[3] = b0.w * QSCALE;
    qB[4] = b1.x * QSCALE; qB[5] = b1.y * QSCALE; qB[6] = b1.z * QSCALE; qB[7] = b1.w * QSCALE;
  }

  float denA = 0.f, denB = 0.f;
  float accA[8], accB[8];
  #pragma unroll
  for (int i = 0; i < 8; ++i) { accA[i] = 0.f; accB[i] = 0.f; }

  const int ntiles = 2 * (rg + 1);                // keys 0 .. base+127
  float* buf0 = &stage[w][0][0];
  float* buf1 = &stage[w][1][0];

  float4 ld0, ld1, ld2, ld3;
  {
    const int t = w;                              // prologue: stage first tile
    ld0 = gsrc[t * 256 +   0 + lane];
    ld1 = gsrc[t * 256 +  64 + lane];
    ld2 = gsrc[t * 256 + 128 + lane];
    ld3 = gsrc[t * 256 + 192 + lane];
    float4* d = (float4*)buf0;
    d[lane] = ld0; d[64 + lane] = ld1; d[128 + lane] = ld2; d[192 + lane] = ld3;
  }

  int it = 0;
  for (int t = w; t < ntiles; t += 2, ++it) {
    float* cur = (it & 1) ? buf1 : buf0;
    float* nxt = (it & 1) ? buf0 : buf1;
    const int tn = t + 2;
    const bool pf = (tn < ntiles);
    if (pf) {                                     // prefetch next tile -> regs
      ld0 = gsrc[tn * 256 +   0 + lane];
      ld1 = gsrc[tn * 256 +  64 + lane];
      ld2 = gsrc[tn * 256 + 128 + lane];
      ld3 = gsrc[tn * 256 + 192 + lane];
    }
    const int k0 = t * 64;
    #pragma unroll 4
    for (int j = 0; j < 64; ++j) {
      const float* kvj = cur + j * 16;            // broadcast ds_read_b128 x4
      const float4 ka = *(const float4*)(kvj);
      const float4 kb = *(const float4*)(kvj + 4);
      const float4 va = *(const float4*)(kvj + 8);
      const float4 vb = *(const float4*)(kvj + 12);
      float dA = qA[0]*ka.x + qA[1]*ka.y + qA[2]*ka.z + qA[3]*ka.w
               + qA[4]*kb.x + qA[5]*kb.y + qA[6]*kb.z + qA[7]*kb.w;
      float dB = qB[0]*ka.x + qB[1]*ka.y + qB[2]*ka.z + qB[3]*ka.w
               + qB[4]*kb.x + qB[5]*kb.y + qB[6]*kb.z + qB[7]*kb.w;
      float sA = RCPF(1.f + EXP2F(-dA));
      float sB = RCPF(1.f + EXP2F(-dB));
      const int kk = k0 + j;
      sA = (kk <= rowA) ? sA : 0.f;               // exact: sigmoid(-1e9)==0
      sB = (kk <= rowB) ? sB : 0.f;
      denA += sA; denB += sB;
      accA[0] += sA*va.x; accA[1] += sA*va.y; accA[2] += sA*va.z; accA[3] += sA*va.w;
      accA[4] += sA*vb.x; accA[5] += sA*vb.y; accA[6] += sA*vb.z; accA[7] += sA*vb.w;
      accB[0] += sB*va.x; accB[1] += sB*va.y; accB[2] += sB*va.z; accB[3] += sB*va.w;
      accB[4] += sB*vb.x; accB[5] += sB*vb.y; accB[6] += sB*vb.z; accB[7] += sB*vb.w;
    }
    if (pf) {                                     // commit prefetched tile
      float4* d = (float4*)nxt;
      d[lane] = ld0; d[64 + lane] = ld1; d[128 + lane] = ld2; d[192 + lane] = ld3;
    }
  }

  // combine the two waves' partials (stride 9 -> 2 lanes/bank, conflict-free)
  if (w == 0) {
    red[lane][0] = denA;
    #pragma unroll
    for (int i = 0; i < 8; ++i) red[lane][1 + i] = accA[i];
    red[lane + 64][0] = denB;
    #pragma unroll
    for (int i = 0; i < 8; ++i) red[lane + 64][1 + i] = accB[i];
  }
  __syncthreads();
  if (w == 1) {
    denA += red[lane][0];
    denB += red[lane + 64][0];
    #pragma unroll
    for (int i = 0; i < 8; ++i) { accA[i] += red[lane][1 + i]; accB[i] += red[lane + 64][1 + i]; }
    const float iA = RCPF(denA);                  // den >= sigmoid(s_qq) > 0
    const float iB = RCPF(denB);
    const int b = bh >> 4, h = bh & 15;
    float* oA = out + ((size_t)(b * SEQ + rowA)) * EDIM + h * HDIM;
    float* oB = out + ((size_t)(b * SEQ + rowB)) * EDIM + h * HDIM;
    *(float4*)(oA)     = make_float4(accA[0]*iA, accA[1]*iA, accA[2]*iA, accA[3]*iA);
    *(float4*)(oA + 4) = make_float4(accA[4]*iA, accA[5]*iA, accA[6]*iA, accA[7]*iA);
    *(float4*)(oB)     = make_float4(accB[0]*iB, accB[1]*iB, accB[2]*iB, accB[3]*iB);
    *(float4*)(oB + 4) = make_float4(accB[4]*iB, accB[5]*iB, accB[6]*iB, accB[7]*iB);
  }
}

// ---------------------------------------------------------------------------
extern "C" void kernel_launch(void* const* d_in, const int* in_sizes, int n_in,
                              void* d_out, int out_size, void* d_ws, size_t ws_size,
                              hipStream_t stream)
{
  const float* x  = (const float*)d_in[0];
  const float* Wq = (const float*)d_in[1];
  const float* bq = (const float*)d_in[2];
  const float* Wk = (const float*)d_in[3];
  const float* bk = (const float*)d_in[4];
  const float* Wv = (const float*)d_in[5];
  const float* bv = (const float*)d_in[6];
  const float* Wo = (const float*)d_in[7];
  const float* bo = (const float*)d_in[8];

  float* ws = (float*)d_ws;
  const size_t QN = (size_t)BATCH * NHEAD * SEQ * HDIM;   // 1,048,576 floats
  float* q    = ws;                 // [bh][s][8]
  float* kv   = ws + QN;            // [bh][s][16]  (K | V interleaved)
  float* attn = ws + 3 * QN;        // [b][s][h*8]
  float* WT   = ws + 4 * QN;        // 4 x 128 x 128

  transpose4_kernel<<<dim3(8, 4), 256, 0, stream>>>(Wq, Wk, Wv, Wo, WT);
  qkv_kernel<<<dim3(NROW / 64, 3), 256, 0, stream>>>(x, WT, bq, bk, bv, q, kv);
  attn_kernel<<<dim3(64 * (SEQ / 128)), 128, 0, stream>>>(q, kv, attn);
  oproj_kernel<<<dim3(NROW / 64), 256, 0, stream>>>(attn, WT + 3 * EDIM * EDIM, bo,
                                                    (float*)d_out);
}

// Round 3
// 217.191 us; speedup vs baseline: 3.6533x; 1.4899x over previous
//
#include <hip/hip_runtime.h>
#include <math.h>

#define EDIM 128
#define NHEAD 16
#define HDIM 8
#define SEQ 2048
#define BATCH 4
#define NROW (BATCH*SEQ)            // 8192
// fold softmax scale AND log2(e) into q so sigmoid = rcp(1 + exp2(-dot))
#define QSCALE (0.35355339059327373f * 1.4426950408889634f)

#if __has_builtin(__builtin_amdgcn_exp2f)
#define EXP2F(x) __builtin_amdgcn_exp2f(x)
#else
#define EXP2F(x) exp2f(x)
#endif
#define RCPF(x) __builtin_amdgcn_rcpf(x)

// ---------------------------------------------------------------------------
// Transpose the 4 weight matrices W[j][i] -> WT[i][j].
// ---------------------------------------------------------------------------
__global__ __launch_bounds__(256)
void transpose4_kernel(const float* __restrict__ W0, const float* __restrict__ W1,
                       const float* __restrict__ W2, const float* __restrict__ W3,
                       float* __restrict__ WT)
{
  const float* W = (blockIdx.y == 0) ? W0 : (blockIdx.y == 1) ? W1
                 : (blockIdx.y == 2) ? W2 : W3;
  float* out = WT + blockIdx.y * EDIM * EDIM;
  const int i0 = blockIdx.x * 16;
  #pragma unroll
  for (int it = 0; it < 8; ++it) {
    int f = threadIdx.x + it * 256;
    int i = i0 + (f >> 7);
    int j = f & 127;
    out[i * EDIM + j] = W[j * EDIM + i];
  }
}

// ---------------------------------------------------------------------------
// out = X @ W^T + b with pre-transposed WT. 64 rows x 128 cols per block.
// Inner loop blocked by 4 i's: x-tile reads are ds_read_b128 (4x fewer LDS
// instructions than per-i b32 reads), WT reads stay coalesced float4.
// mode 0: Q -> [bh][s][8]; mode 1: K -> KV[bh][s][0..7];
// mode 2: V -> KV[bh][s][8..15]; mode 3: row-major [rows][128].
// ---------------------------------------------------------------------------
__device__ __forceinline__
void proj_body(const float* __restrict__ X, const float* __restrict__ WT,
               const float* __restrict__ bias, float* __restrict__ out, int mode)
{
  __shared__ float xs[64][EDIM];                  // 32 KB
  const int tid = threadIdx.x;
  const int row0 = blockIdx.x * 64;

  const float4* src = (const float4*)(X + row0 * EDIM);
  float4* dst = (float4*)(&xs[0][0]);
  #pragma unroll
  for (int t = 0; t < 8; ++t) dst[tid + t * 256] = src[tid + t * 256];
  __syncthreads();

  const int tc = tid & 31;
  const int tr = tid >> 5;                        // 0..7 (8 rows each)
  const int col0 = tc * 4;

  float acc[8][4];
  #pragma unroll
  for (int r = 0; r < 8; ++r)
    #pragma unroll
    for (int c = 0; c < 4; ++c) acc[r][c] = 0.f;

  #pragma unroll 2
  for (int ib = 0; ib < EDIM / 4; ++ib) {
    const float4 w0 = *(const float4*)(WT + (4 * ib + 0) * EDIM + col0);
    const float4 w1 = *(const float4*)(WT + (4 * ib + 1) * EDIM + col0);
    const float4 w2 = *(const float4*)(WT + (4 * ib + 2) * EDIM + col0);
    const float4 w3 = *(const float4*)(WT + (4 * ib + 3) * EDIM + col0);
    #pragma unroll
    for (int r = 0; r < 8; ++r) {
      const float4 x4 = *(const float4*)(&xs[tr * 8 + r][ib * 4]);  // b128 broadcast
      acc[r][0] += x4.x * w0.x + x4.y * w1.x + x4.z * w2.x + x4.w * w3.x;
      acc[r][1] += x4.x * w0.y + x4.y * w1.y + x4.z * w2.y + x4.w * w3.y;
      acc[r][2] += x4.x * w0.z + x4.y * w1.z + x4.z * w2.z + x4.w * w3.z;
      acc[r][3] += x4.x * w0.w + x4.y * w1.w + x4.z * w2.w + x4.w * w3.w;
    }
  }

  const float4 b4 = *(const float4*)(bias + col0);
  #pragma unroll
  for (int r = 0; r < 8; ++r) {
    const int grow = row0 + tr * 8 + r;
    const float4 o = make_float4(acc[r][0] + b4.x, acc[r][1] + b4.y,
                                 acc[r][2] + b4.z, acc[r][3] + b4.w);
    if (mode == 3) {
      *(float4*)(out + (size_t)grow * EDIM + col0) = o;
    } else {
      const int b = grow >> 11, s = grow & (SEQ - 1);
      const int h = col0 >> 3, d0 = col0 & 7;
      const size_t bhs = (size_t)(b * NHEAD + h) * SEQ + s;
      if (mode == 0)      *(float4*)(out + bhs * 8  + d0) = o;
      else if (mode == 1) *(float4*)(out + bhs * 16 + d0) = o;
      else                *(float4*)(out + bhs * 16 + 8 + d0) = o;
    }
  }
}

__global__ __launch_bounds__(256)
void qkv_kernel(const float* __restrict__ X, const float* __restrict__ WT,
                const float* __restrict__ bq, const float* __restrict__ bk,
                const float* __restrict__ bv,
                float* __restrict__ q, float* __restrict__ kv)
{
  const int m = blockIdx.y;
  const float* wt   = WT + m * EDIM * EDIM;
  const float* bias = (m == 0) ? bq : (m == 1) ? bk : bv;
  float* out        = (m == 0) ? q  : kv;
  proj_body(X, wt, bias, out, m);
}

__global__ __launch_bounds__(256)
void oproj_kernel(const float* __restrict__ A, const float* __restrict__ WTo,
                  const float* __restrict__ bo, float* __restrict__ out)
{
  proj_body(A, WTo, bo, out, 3);
}

// ---------------------------------------------------------------------------
// Attention inner tile: 64 keys from LDS, 2 rows/lane. MASKED only for the
// two diagonal tiles (t >= 2m); bulk tiles skip the causal compare.
// ---------------------------------------------------------------------------
template<bool MASKED>
__device__ __forceinline__
void attn_tile(const float* __restrict__ cur, int k0, int rowA, int rowB,
               const float* __restrict__ qA, const float* __restrict__ qB,
               float& denA, float& denB,
               float* __restrict__ accA, float* __restrict__ accB)
{
  #pragma unroll 4
  for (int j = 0; j < 64; ++j) {
    const float* kvj = cur + j * 16;              // broadcast ds_read_b128 x4
    const float4 ka = *(const float4*)(kvj);
    const float4 kb = *(const float4*)(kvj + 4);
    const float4 va = *(const float4*)(kvj + 8);
    const float4 vb = *(const float4*)(kvj + 12);
    float dA = qA[0]*ka.x + qA[1]*ka.y + qA[2]*ka.z + qA[3]*ka.w
             + qA[4]*kb.x + qA[5]*kb.y + qA[6]*kb.z + qA[7]*kb.w;
    float dB = qB[0]*ka.x + qB[1]*ka.y + qB[2]*ka.z + qB[3]*ka.w
             + qB[4]*kb.x + qB[5]*kb.y + qB[6]*kb.z + qB[7]*kb.w;
    float sA = RCPF(1.f + EXP2F(-dA));
    float sB = RCPF(1.f + EXP2F(-dB));
    if (MASKED) {
      const int kk = k0 + j;
      sA = (kk <= rowA) ? sA : 0.f;               // exact: sigmoid(-1e9)==0
      sB = (kk <= rowB) ? sB : 0.f;
    }
    denA += sA; denB += sB;
    accA[0] += sA*va.x; accA[1] += sA*va.y; accA[2] += sA*va.z; accA[3] += sA*va.w;
    accA[4] += sA*vb.x; accA[5] += sA*vb.y; accA[6] += sA*vb.z; accA[7] += sA*vb.w;
    accB[0] += sB*va.x; accB[1] += sB*va.y; accB[2] += sB*va.z; accB[3] += sB*va.w;
    accB[4] += sB*vb.x; accB[5] += sB*vb.y; accB[6] += sB*vb.z; accB[7] += sB*vb.w;
  }
}

// ---------------------------------------------------------------------------
// Causal sigmoid-attention v3.
// Block = (bh, m): 256 threads (4 waves), rows 128m..128m+127 of head bh.
// Lane owns rowA = 128m+lane (tile 2m) and rowB = 128m+64+lane (tile 2m+1).
// The 4 waves take key-tiles t = w, w+4, ... < 2(m+1) (wave-private LDS
// double-buffered staging, coalesced global_load_dwordx4), then combine
// partials through LDS. Heavy blocks launch first (m = 15 - blockIdx>>6)
// for LPT balance; bh = blockIdx&63 keeps a bh's KV on one XCD.
// ---------------------------------------------------------------------------
__global__ __launch_bounds__(256)
void attn_kernel(const float* __restrict__ Q, const float* __restrict__ KV,
                 float* __restrict__ out)
{
  __shared__ float stage[4][2][64 * 16];          // 32 KB
  __shared__ float red[4][128][9];                // 18 KB

  const int bh   = blockIdx.x & 63;
  const int m    = 15 - (blockIdx.x >> 6);        // LPT: heavy first
  const int w    = threadIdx.x >> 6;
  const int lane = threadIdx.x & 63;
  const int rowA = m * 128 + lane;
  const int rowB = m * 128 + 64 + lane;
  const int ntiles = 2 * (m + 1);

  const float4* gsrc = (const float4*)(KV + (size_t)bh * SEQ * 16);

  float qA[8], qB[8];
  {
    const float* qpA = Q + ((size_t)bh * SEQ + rowA) * 8;
    const float* qpB = Q + ((size_t)bh * SEQ + rowB) * 8;
    const float4 a0 = *(const float4*)qpA, a1 = *(const float4*)(qpA + 4);
    const float4 b0 = *(const float4*)qpB, b1 = *(const float4*)(qpB + 4);
    qA[0] = a0.x * QSCALE; qA[1] = a0.y * QSCALE; qA[2] = a0.z * QSCALE; qA[3] = a0.w * QSCALE;
    qA[4] = a1.x * QSCALE; qA[5] = a1.y * QSCALE; qA[6] = a1.z * QSCALE; qA[7] = a1.w * QSCALE;
    qB[0] = b0.x * QSCALE; qB[1] = b0.y * QSCALE; qB[2] = b0.z * QSCALE; qB[3] = b0.w * QSCALE;
    qB[4] = b1.x * QSCALE; qB[5] = b1.y * QSCALE; qB[6] = b1.z * QSCALE; qB[7] = b1.w * QSCALE;
  }

  float denA = 0.f, denB = 0.f;
  float accA[8], accB[8];
  #pragma unroll
  for (int i = 0; i < 8; ++i) { accA[i] = 0.f; accB[i] = 0.f; }

  float* buf0 = &stage[w][0][0];
  float* buf1 = &stage[w][1][0];

  float4 ld0, ld1, ld2, ld3;
  if (w < ntiles) {                               // prologue: stage first tile
    ld0 = gsrc[w * 256 +   0 + lane];
    ld1 = gsrc[w * 256 +  64 + lane];
    ld2 = gsrc[w * 256 + 128 + lane];
    ld3 = gsrc[w * 256 + 192 + lane];
    float4* d = (float4*)buf0;
    d[lane] = ld0; d[64 + lane] = ld1; d[128 + lane] = ld2; d[192 + lane] = ld3;
  }

  int it = 0;
  for (int t = w; t < ntiles; t += 4, ++it) {
    float* cur = (it & 1) ? buf1 : buf0;
    float* nxt = (it & 1) ? buf0 : buf1;
    const int tn = t + 4;
    const bool pf = (tn < ntiles);
    if (pf) {                                     // prefetch next tile -> regs
      ld0 = gsrc[tn * 256 +   0 + lane];
      ld1 = gsrc[tn * 256 +  64 + lane];
      ld2 = gsrc[tn * 256 + 128 + lane];
      ld3 = gsrc[tn * 256 + 192 + lane];
    }
    const int k0 = t * 64;
    if (t >= 2 * m)
      attn_tile<true >(cur, k0, rowA, rowB, qA, qB, denA, denB, accA, accB);
    else
      attn_tile<false>(cur, k0, rowA, rowB, qA, qB, denA, denB, accA, accB);
    if (pf) {                                     // commit prefetched tile
      float4* d = (float4*)nxt;
      d[lane] = ld0; d[64 + lane] = ld1; d[128 + lane] = ld2; d[192 + lane] = ld3;
    }
  }

  // write per-wave partials (stride 9 floats -> 2 lanes/bank, conflict-free)
  red[w][lane][0] = denA;
  #pragma unroll
  for (int i = 0; i < 8; ++i) red[w][lane][1 + i] = accA[i];
  red[w][64 + lane][0] = denB;
  #pragma unroll
  for (int i = 0; i < 8; ++i) red[w][64 + lane][1 + i] = accB[i];
  __syncthreads();

  if (w == 0) {
    float dA = 0.f, dB = 0.f, aA[8], aB[8];
    #pragma unroll
    for (int i = 0; i < 8; ++i) { aA[i] = 0.f; aB[i] = 0.f; }
    #pragma unroll
    for (int ww = 0; ww < 4; ++ww) {
      dA += red[ww][lane][0];
      dB += red[ww][64 + lane][0];
      #pragma unroll
      for (int i = 0; i < 8; ++i) {
        aA[i] += red[ww][lane][1 + i];
        aB[i] += red[ww][64 + lane][1 + i];
      }
    }
    const float iA = RCPF(dA);                    // den >= sigmoid(s_qq) > 0
    const float iB = RCPF(dB);
    const int b = bh >> 4, h = bh & 15;
    float* oA = out + ((size_t)(b * SEQ + rowA)) * EDIM + h * HDIM;
    float* oB = out + ((size_t)(b * SEQ + rowB)) * EDIM + h * HDIM;
    *(float4*)(oA)     = make_float4(aA[0]*iA, aA[1]*iA, aA[2]*iA, aA[3]*iA);
    *(float4*)(oA + 4) = make_float4(aA[4]*iA, aA[5]*iA, aA[6]*iA, aA[7]*iA);
    *(float4*)(oB)     = make_float4(aB[0]*iB, aB[1]*iB, aB[2]*iB, aB[3]*iB);
    *(float4*)(oB + 4) = make_float4(aB[4]*iB, aB[5]*iB, aB[6]*iB, aB[7]*iB);
  }
}

// ---------------------------------------------------------------------------
extern "C" void kernel_launch(void* const* d_in, const int* in_sizes, int n_in,
                              void* d_out, int out_size, void* d_ws, size_t ws_size,
                              hipStream_t stream)
{
  const float* x  = (const float*)d_in[0];
  const float* Wq = (const float*)d_in[1];
  const float* bq = (const float*)d_in[2];
  const float* Wk = (const float*)d_in[3];
  const float* bk = (const float*)d_in[4];
  const float* Wv = (const float*)d_in[5];
  const float* bv = (const float*)d_in[6];
  const float* Wo = (const float*)d_in[7];
  const float* bo = (const float*)d_in[8];

  float* ws = (float*)d_ws;
  const size_t QN = (size_t)BATCH * NHEAD * SEQ * HDIM;   // 1,048,576 floats
  float* q    = ws;                 // [bh][s][8]
  float* kv   = ws + QN;            // [bh][s][16]  (K | V interleaved)
  float* attn = ws + 3 * QN;        // [b][s][h*8]
  float* WT   = ws + 4 * QN;        // 4 x 128 x 128

  transpose4_kernel<<<dim3(8, 4), 256, 0, stream>>>(Wq, Wk, Wv, Wo, WT);
  qkv_kernel<<<dim3(NROW / 64, 3), 256, 0, stream>>>(x, WT, bq, bk, bv, q, kv);
  attn_kernel<<<dim3(64 * 16), 256, 0, stream>>>(q, kv, attn);
  oproj_kernel<<<dim3(NROW / 64), 256, 0, stream>>>(attn, WT + 3 * EDIM * EDIM, bo,
                                                    (float*)d_out);
}